// Round 3
// baseline (148.263 us; speedup 1.0000x reference)
//
#include <hip/hip_runtime.h>

// Problem constants
#define B_    16
#define H_    544
#define W_    960
#define HW    (H_ * W_)          // 522240
#define HW4   (HW / 4)           // 130560 float4 groups per channel plane
#define BLOCK 256
#define BX    85                 // blocks per batch: 85 * 1536 = 130560 exactly
#define PSTRIDE 96               // padded partials stride per batch (85 used)

// ws layout: three arrays [16][96] floats: sum | bright | dark  (18 KB total)

__global__ __launch_bounds__(BLOCK) void reduce_kernel(
        const float* __restrict__ img, float* __restrict__ ws) {
    const int tid = threadIdx.x;
    const int bx  = blockIdx.x;          // 0..84
    const int b   = blockIdx.y;          // 0..15

    const float4* p0 = (const float4*)(img + (size_t)b * 3 * HW);
    const float4* p1 = p0 + HW4;
    const float4* p2 = p1 + HW4;

    const float inv3 = 1.0f / 3.0f;
    float s = 0.0f, br = 0.0f, dk = 0.0f;

    // 3 iterations x 6 independent 16B loads; 1536 float4s per block total
    #pragma unroll
    for (int it = 0; it < 3; ++it) {
        const int i0 = bx * 1536 + it * 512 + tid;
        const int i1 = i0 + 256;

        float4 a0 = p0[i0];
        float4 a1 = p0[i1];
        float4 c0 = p1[i0];
        float4 c1 = p1[i1];
        float4 d0 = p2[i0];
        float4 d1 = p2[i1];

        float g[8];
        g[0] = (a0.x + c0.x + d0.x) * inv3;
        g[1] = (a0.y + c0.y + d0.y) * inv3;
        g[2] = (a0.z + c0.z + d0.z) * inv3;
        g[3] = (a0.w + c0.w + d0.w) * inv3;
        g[4] = (a1.x + c1.x + d1.x) * inv3;
        g[5] = (a1.y + c1.y + d1.y) * inv3;
        g[6] = (a1.z + c1.z + d1.z) * inv3;
        g[7] = (a1.w + c1.w + d1.w) * inv3;

        #pragma unroll
        for (int k = 0; k < 8; ++k) {
            s  += g[k];
            br += (g[k] >= 0.75f && g[k] <= 1.0f) ? 1.0f : 0.0f;
            dk += (g[k] >= 0.0f  && g[k] <  0.25f) ? 1.0f : 0.0f;
        }
    }

    // wave-64 butterfly reduce
    #pragma unroll
    for (int off = 32; off > 0; off >>= 1) {
        s  += __shfl_xor(s,  off);
        br += __shfl_xor(br, off);
        dk += __shfl_xor(dk, off);
    }

    __shared__ float sm[3][4];
    const int lane = tid & 63;
    const int wave = tid >> 6;
    if (lane == 0) { sm[0][wave] = s; sm[1][wave] = br; sm[2][wave] = dk; }
    __syncthreads();

    if (tid == 0) {
        float ts = sm[0][0] + sm[0][1] + sm[0][2] + sm[0][3];
        float tb = sm[1][0] + sm[1][1] + sm[1][2] + sm[1][3];
        float td = sm[2][0] + sm[2][1] + sm[2][2] + sm[2][3];
        const int slot = b * PSTRIDE + bx;
        ws[slot]                      = ts;
        ws[B_ * PSTRIDE + slot]       = tb;
        ws[2 * B_ * PSTRIDE + slot]   = td;
    }
}

// out layout [5,16]: dr | bright_avg | gaps | e1 | e2
// One block, 256 threads: 16 threads per batch reduce 85 partials each.
__global__ __launch_bounds__(256) void finalize_kernel(
        const float* __restrict__ ws,
        const float* __restrict__ be1,
        const float* __restrict__ be2,
        float* __restrict__ out) {
    __shared__ float s_ba[B_], s_gap[B_];
    const int t   = threadIdx.x;
    const int b   = t >> 4;      // batch 0..15 (16 threads each, 16-aligned in wave)
    const int sub = t & 15;

    const float* ws_s = ws;
    const float* ws_b = ws + B_ * PSTRIDE;
    const float* ws_d = ws + 2 * B_ * PSTRIDE;

    float s = 0.0f, br = 0.0f, dk = 0.0f;
    #pragma unroll
    for (int k = 0; k < 6; ++k) {
        int idx = sub + 16 * k;
        if (idx < BX) {
            s  += ws_s[b * PSTRIDE + idx];
            br += ws_b[b * PSTRIDE + idx];
            dk += ws_d[b * PSTRIDE + idx];
        }
    }
    // reduce within each aligned 16-lane group
    #pragma unroll
    for (int off = 8; off > 0; off >>= 1) {
        s  += __shfl_xor(s,  off);
        br += __shfl_xor(br, off);
        dk += __shfl_xor(dk, off);
    }

    if (sub == 0) {
        float ba = s / (float)HW;
        float dr = br / (dk + 1e-5f);
        // jnp.select: first true wins. BASE_GAP = 0.5
        float gap;
        if (dr > 1.0f && ba > 0.4f && ba < 0.6f)       gap = 1.0f;    // 0.5*2.0
        else if (ba <= 0.3f)                           gap = 0.25f;   // 0.5*0.5
        else if (ba >= 0.7f)                           gap = 0.25f;   // 0.5*0.5
        else if (dr <= 1.0f && ba > 0.3f && ba < 0.7f) gap = 0.375f;  // 0.5*0.75
        else                                           gap = 0.0f;

        out[b]          = dr;
        out[B_ + b]     = ba;
        out[2 * B_ + b] = gap;
        s_ba[b]  = ba;
        s_gap[b] = gap;
    }
    __syncthreads();

    if (t < B_) {
        const float bl = s_ba[B_ - 1];
        const float gl = s_gap[B_ - 1];
        const float SCALE = 1.7f;
        float e1, e2;
        if (bl <= 0.25f) {
            e1 = be1[t] + 0.5f * gl * SCALE;
            e2 = be2[t] + 0.5f * gl * SCALE;
        } else if (bl >= 0.75f) {
            e1 = be1[t] - 0.5f * gl * SCALE;
            e2 = be2[t] - 0.5f * gl * SCALE;
        } else {
            e1 = be1[t] - 0.3f * gl;
            e2 = be2[t] + 0.7f * gl;
        }
        out[3 * B_ + t] = e1;
        out[4 * B_ + t] = e2;
    }
}

extern "C" void kernel_launch(void* const* d_in, const int* in_sizes, int n_in,
                              void* d_out, int out_size, void* d_ws, size_t ws_size,
                              hipStream_t stream) {
    const float* img = (const float*)d_in[0];   // [16,3,544,960] fp32
    const float* be1 = (const float*)d_in[1];   // [16] fp32
    const float* be2 = (const float*)d_in[2];   // [16] fp32
    float* out = (float*)d_out;                 // [5,16] fp32
    float* ws  = (float*)d_ws;                  // uses 18 KB

    reduce_kernel<<<dim3(BX, B_), BLOCK, 0, stream>>>(img, ws);
    finalize_kernel<<<1, 256, 0, stream>>>(ws, be1, be2, out);
}

// Round 4
// 146.655 us; speedup vs baseline: 1.0110x; 1.0110x over previous
//
#include <hip/hip_runtime.h>

// Problem constants
#define B_    16
#define H_    544
#define W_    960
#define HW    (H_ * W_)          // 522240
#define HW4   (HW / 4)           // 130560 float4 groups per channel plane
#define BLOCK 256
#define G_    5                  // float4 groups of 256 per plane per block
#define BX    102                // blocks per batch: 102 * 1280 = 130560 exactly
#define PSTRIDE 112              // padded partials stride per batch (102 used)

// ws layout: three arrays [16][112] floats: sum | bright | dark  (21 KB total)

__global__ __launch_bounds__(BLOCK) void reduce_kernel(
        const float* __restrict__ img, float* __restrict__ ws) {
    const int tid = threadIdx.x;
    const int bx  = blockIdx.x;          // 0..101
    const int b   = blockIdx.y;          // 0..15

    const float4* p0 = (const float4*)(img + (size_t)b * 3 * HW);
    const float4* p1 = p0 + HW4;
    const float4* p2 = p1 + HW4;

    const int base = bx * (G_ * BLOCK) + tid;

    // 15 independent 16B loads — all issued before any use
    float4 va[G_], vc[G_], vd[G_];
    #pragma unroll
    for (int k = 0; k < G_; ++k) va[k] = p0[base + k * BLOCK];
    #pragma unroll
    for (int k = 0; k < G_; ++k) vc[k] = p1[base + k * BLOCK];
    #pragma unroll
    for (int k = 0; k < G_; ++k) vd[k] = p2[base + k * BLOCK];

    const float inv3 = 1.0f / 3.0f;
    float s = 0.0f, br = 0.0f, dk = 0.0f;
    #pragma unroll
    for (int k = 0; k < G_; ++k) {
        float g0 = (va[k].x + vc[k].x + vd[k].x) * inv3;
        float g1 = (va[k].y + vc[k].y + vd[k].y) * inv3;
        float g2 = (va[k].z + vc[k].z + vd[k].z) * inv3;
        float g3 = (va[k].w + vc[k].w + vd[k].w) * inv3;
        s  += g0 + g1 + g2 + g3;
        br += ((g0 >= 0.75f && g0 <= 1.0f) ? 1.0f : 0.0f)
            + ((g1 >= 0.75f && g1 <= 1.0f) ? 1.0f : 0.0f)
            + ((g2 >= 0.75f && g2 <= 1.0f) ? 1.0f : 0.0f)
            + ((g3 >= 0.75f && g3 <= 1.0f) ? 1.0f : 0.0f);
        dk += ((g0 >= 0.0f && g0 < 0.25f) ? 1.0f : 0.0f)
            + ((g1 >= 0.0f && g1 < 0.25f) ? 1.0f : 0.0f)
            + ((g2 >= 0.0f && g2 < 0.25f) ? 1.0f : 0.0f)
            + ((g3 >= 0.0f && g3 < 0.25f) ? 1.0f : 0.0f);
    }

    // wave-64 butterfly reduce
    #pragma unroll
    for (int off = 32; off > 0; off >>= 1) {
        s  += __shfl_xor(s,  off);
        br += __shfl_xor(br, off);
        dk += __shfl_xor(dk, off);
    }

    __shared__ float sm[3][4];
    const int lane = tid & 63;
    const int wave = tid >> 6;
    if (lane == 0) { sm[0][wave] = s; sm[1][wave] = br; sm[2][wave] = dk; }
    __syncthreads();

    if (tid == 0) {
        float ts = sm[0][0] + sm[0][1] + sm[0][2] + sm[0][3];
        float tb = sm[1][0] + sm[1][1] + sm[1][2] + sm[1][3];
        float td = sm[2][0] + sm[2][1] + sm[2][2] + sm[2][3];
        const int slot = b * PSTRIDE + bx;
        ws[slot]                      = ts;
        ws[B_ * PSTRIDE + slot]       = tb;
        ws[2 * B_ * PSTRIDE + slot]   = td;
    }
}

// out layout [5,16]: dr | bright_avg | gaps | e1 | e2
// One block, 256 threads: 16 threads per batch reduce 102 partials each.
__global__ __launch_bounds__(256) void finalize_kernel(
        const float* __restrict__ ws,
        const float* __restrict__ be1,
        const float* __restrict__ be2,
        float* __restrict__ out) {
    __shared__ float s_ba[B_], s_gap[B_];
    const int t   = threadIdx.x;
    const int b   = t >> 4;      // batch 0..15 (16 threads each, 16-aligned in wave)
    const int sub = t & 15;

    const float* ws_s = ws;
    const float* ws_b = ws + B_ * PSTRIDE;
    const float* ws_d = ws + 2 * B_ * PSTRIDE;

    float s = 0.0f, br = 0.0f, dk = 0.0f;
    #pragma unroll
    for (int k = 0; k < 7; ++k) {
        int idx = sub + 16 * k;
        if (idx < BX) {
            s  += ws_s[b * PSTRIDE + idx];
            br += ws_b[b * PSTRIDE + idx];
            dk += ws_d[b * PSTRIDE + idx];
        }
    }
    // reduce within each aligned 16-lane group
    #pragma unroll
    for (int off = 8; off > 0; off >>= 1) {
        s  += __shfl_xor(s,  off);
        br += __shfl_xor(br, off);
        dk += __shfl_xor(dk, off);
    }

    if (sub == 0) {
        float ba = s / (float)HW;
        float dr = br / (dk + 1e-5f);
        // jnp.select: first true wins. BASE_GAP = 0.5
        float gap;
        if (dr > 1.0f && ba > 0.4f && ba < 0.6f)       gap = 1.0f;    // 0.5*2.0
        else if (ba <= 0.3f)                           gap = 0.25f;   // 0.5*0.5
        else if (ba >= 0.7f)                           gap = 0.25f;   // 0.5*0.5
        else if (dr <= 1.0f && ba > 0.3f && ba < 0.7f) gap = 0.375f;  // 0.5*0.75
        else                                           gap = 0.0f;

        out[b]          = dr;
        out[B_ + b]     = ba;
        out[2 * B_ + b] = gap;
        s_ba[b]  = ba;
        s_gap[b] = gap;
    }
    __syncthreads();

    if (t < B_) {
        const float bl = s_ba[B_ - 1];
        const float gl = s_gap[B_ - 1];
        const float SCALE = 1.7f;
        float e1, e2;
        if (bl <= 0.25f) {
            e1 = be1[t] + 0.5f * gl * SCALE;
            e2 = be2[t] + 0.5f * gl * SCALE;
        } else if (bl >= 0.75f) {
            e1 = be1[t] - 0.5f * gl * SCALE;
            e2 = be2[t] - 0.5f * gl * SCALE;
        } else {
            e1 = be1[t] - 0.3f * gl;
            e2 = be2[t] + 0.7f * gl;
        }
        out[3 * B_ + t] = e1;
        out[4 * B_ + t] = e2;
    }
}

extern "C" void kernel_launch(void* const* d_in, const int* in_sizes, int n_in,
                              void* d_out, int out_size, void* d_ws, size_t ws_size,
                              hipStream_t stream) {
    const float* img = (const float*)d_in[0];   // [16,3,544,960] fp32
    const float* be1 = (const float*)d_in[1];   // [16] fp32
    const float* be2 = (const float*)d_in[2];   // [16] fp32
    float* out = (float*)d_out;                 // [5,16] fp32
    float* ws  = (float*)d_ws;                  // uses 21 KB

    reduce_kernel<<<dim3(BX, B_), BLOCK, 0, stream>>>(img, ws);
    finalize_kernel<<<1, 256, 0, stream>>>(ws, be1, be2, out);
}